// Round 16
// baseline (97.843 us; speedup 1.0000x reference)
//
#include <hip/hip_runtime.h>
#include <hip/hip_bf16.h>

#define NB 16
#define CI 512
#define CO 512
#define HW 1024
#define SD 512
#define EPSI 1e-8f

typedef __attribute__((ext_vector_type(8))) short bf16x8;
typedef __attribute__((ext_vector_type(16))) float f32x16;
typedef __attribute__((ext_vector_type(4))) unsigned int u32x4;

#define GLOAD_LDS16(g, l) __builtin_amdgcn_global_load_lds( \
    (const __attribute__((address_space(1))) unsigned int*)(const void*)(g), \
    (__attribute__((address_space(3))) unsigned int*)(void*)(l), 16, 0, 0)
#define SCHED0() __builtin_amdgcn_sched_barrier(0)
#define SBAR()   __builtin_amdgcn_s_barrier()

// ---- merged prep: blocks 0..2047 style GEMV; blocks 2048..3071 wprep (+zpage)
__global__ void k_prep(const float* __restrict__ w, const float* __restrict__ sw,
                       const float* __restrict__ sb, const float* __restrict__ wt,
                       float* __restrict__ style, float* __restrict__ wsq,
                       __hip_bfloat16* __restrict__ wtb, u32x4* __restrict__ zpage) {
    if (blockIdx.x < 2048) {
        int gw = (blockIdx.x * 256 + threadIdx.x) >> 6;   // 0..8191
        int l = threadIdx.x & 63;
        int b = gw >> 9, c = gw & 511;
        const float4* wr = (const float4*)(w + b * SD) + (l << 1);
        const float4* sr = (const float4*)(sw + c * SD) + (l << 1);
        float4 a0 = wr[0], a1 = wr[1], q0 = sr[0], q1 = sr[1];
        float acc = a0.x * q0.x + a0.y * q0.y + a0.z * q0.z + a0.w * q0.w
                  + a1.x * q1.x + a1.y * q1.y + a1.z * q1.z + a1.w * q1.w;
#pragma unroll
        for (int off = 32; off > 0; off >>= 1) acc += __shfl_down(acc, off);
        if (l == 0) style[gw] = acc + sb[c];
    } else {
        if (blockIdx.x == 2048 && threadIdx.x < 64)
            zpage[threadIdx.x] = (u32x4){0, 0, 0, 0};
        int idx = (blockIdx.x - 2048) * 256 + threadIdx.x;   // co*512+ci
        const float* p = wt + (size_t)idx * 9;
        float a = 0.f;
#pragma unroll
        for (int t = 0; t < 9; ++t) {
            float v = p[t];
            a += v * v;
            wtb[t * (CO * CI) + idx] = __float2bfloat16(v);
        }
        wsq[idx] = a;
    }
}

// ---- merged: blocks 0..4095 xs-transpose (short8 stores); blocks 4096..6143 demod
__global__ void k_xs2(const float* __restrict__ x, const float* __restrict__ style,
                      const float* __restrict__ wsq, __hip_bfloat16* __restrict__ xs,
                      float* __restrict__ dv) {
    __shared__ float tile[32][66];     // [px][ci], +2 pad
    if (blockIdx.x < 4096) {
        int b = blockIdx.x >> 8, c0 = ((blockIdx.x >> 5) & 7) * 64, p0 = (blockIdx.x & 31) * 32;
        int tx = threadIdx.x & 31, ty = threadIdx.x >> 5;   // ty 0..7
#pragma unroll
        for (int i = 0; i < 8; ++i) {
            int ci = i * 8 + ty;
            tile[tx][ci] = x[((size_t)b * CI + c0 + ci) * HW + p0 + tx] * style[b * CI + c0 + ci];
        }
        __syncthreads();
        int r = threadIdx.x >> 3, kc = threadIdx.x & 7;
        union { bf16x8 v; __hip_bfloat16 h[8]; } U;
#pragma unroll
        for (int i = 0; i < 8; ++i)
            U.h[i] = __float2bfloat16(tile[r][kc * 8 + i]);
        *(bf16x8*)(xs + ((size_t)b * HW + p0 + r) * CI + c0 + kc * 8) = U.v;
    } else {
        int gw = ((blockIdx.x - 4096) * 256 + threadIdx.x) >> 6;   // 0..8191
        int l = threadIdx.x & 63;
        int b = gw >> 9, co = gw & 511;
        const float4* st = (const float4*)(style + b * CI) + (l << 1);
        const float4* wq = (const float4*)(wsq + (size_t)co * CI) + (l << 1);
        float4 s0 = st[0], s1 = st[1], q0 = wq[0], q1 = wq[1];
        float acc = s0.x * s0.x * q0.x + s0.y * s0.y * q0.y + s0.z * s0.z * q0.z + s0.w * s0.w * q0.w
                  + s1.x * s1.x * q1.x + s1.y * s1.y * q1.y + s1.z * s1.z * q1.z + s1.w * s1.w * q1.w;
#pragma unroll
        for (int off = 32; off > 0; off >>= 1) acc += __shfl_down(acc, off);
        if (l == 0) dv[gw] = rsqrtf(acc + EPSI);
    }
}

// ---- conv: R4 geometry (128co x 128px x 2 batches, 8 waves m2n2) with T3-style
// two-barrier phase schedule: interval A = {ds_read next-tap fragments -> REGISTERS,
// issue W(s+2)/X' DMA}; interval M = {pure 16-MFMA from registers}. The lgkm wait for
// A's ds_reads completes during B2 resync, so M has zero internal LDS stalls.
// W triple-buffer (buf = t%3, static), X double-buffer, counted-vmcnt ledger.
#define XS_BYTES 52224               // one X buffer: 2 batches x 6 rows x 34 cols x 128 B
#define WBUF_BYTES 16384             // one W buffer: 128co x 64ci bf16
#define SMEM_TOTAL (2 * XS_BYTES + 3 * WBUF_BYTES)   // 153600

extern "C" __global__ __launch_bounds__(512, 2) void k_conv(
        const __hip_bfloat16* __restrict__ wtb,
        const __hip_bfloat16* __restrict__ xs,
        const float* __restrict__ dvec,
        const char* __restrict__ zpage,
        float* __restrict__ out) {
    extern __shared__ char smem[];
    char* Xs  = smem;                    // 2 buffers
    char* Wsb = smem + 2 * XS_BYTES;     // 3 buffers

    const int tid  = threadIdx.x;
    const int lane = tid & 63;
    const int l31  = lane & 31;
    const int wv   = tid >> 6;           // 0..7
    const int wb   = wv >> 2;            // batch within pair
    const int wr   = (wv >> 1) & 1;      // co half (64)
    const int wn   = wv & 1;             // px half (64)

    // XCD-aware swizzle: co-tile pinned per XCD pair so W panel stays L2-resident
    int bid = blockIdx.x;
    int xcd = bid & 7, idx = bid >> 3;
    int cot = xcd >> 1;
    int px8 = idx & 7;
    int bp  = (idx >> 3) | ((xcd & 1) << 2);
    const int co0 = cot * 128;
    const int p0  = px8 * 128;
    const int y0  = px8 * 4;
    const int b0  = bp * 2;
    const int b   = b0 + wb;

    // zero halo pad columns rx=0 and rx=33 in BOTH X buffers (persist whole kernel)
    if (tid < 192) {
        int g = tid & 7;
        int rx = ((tid >> 3) & 1) ? 33 : 0;
        int row = tid >> 4;                  // bb*6+ry, 0..11
        int off = (row * 34 + rx) * 128 + g * 16;
        *(u32x4*)(Xs + off) = (u32x4){0, 0, 0, 0};
        *(u32x4*)(Xs + XS_BYTES + off) = (u32x4){0, 0, 0, 0};
    }

    const int srcgW = (lane & 7) ^ (lane >> 3);

    // W stage: 16 segments, 2 per wave. stage s -> buffer s%3 (= tap%3, static)
    auto issueW = [&](int tap, int cin, int bufi) {
        const __hip_bfloat16* wsrc = wtb + ((size_t)tap * CO + co0) * CI + cin;
        char* wdst = Wsb + bufi * WBUF_BYTES;
#pragma unroll
        for (int k = 0; k < 2; ++k) {
            int seg = k * 8 + wv;
            int co_l = seg * 8 + (lane >> 3);
            GLOAD_LDS16(wsrc + co_l * CI + srcgW * 8, wdst + seg * 1024);
        }
    };
    // X stage: 48 segments, 6 per wave; OOB rows stream zeros from zpage (uniform ledger)
    auto issueX = [&](char* Xdst, int cin) {
#pragma unroll
        for (int k = 0; k < 6; ++k) {
            int sid = k * 8 + wv;
            int bb = (sid >= 24) ? 1 : 0;
            int rem = sid - bb * 24;
            int ry = rem >> 2, seg = rem & 3;
            int rx0 = 1 + seg * 8;
            char* ldst = Xdst + ((bb * 6 + ry) * 34 + rx0) * 128;
            int y = y0 - 1 + ry;
            int rx = rx0 + (lane >> 3);
            int srcg = (lane & 7) ^ (rx & 7);
            if ((unsigned)y < 32u)
                GLOAD_LDS16(xs + ((size_t)(b0 + bb) * HW + (y << 5) + (rx - 1)) * CI + cin + srcg * 8, ldst);
            else
                GLOAD_LDS16(zpage, ldst);
        }
    };

    f32x16 acc[2][2];
#pragma unroll
    for (int m = 0; m < 2; ++m)
#pragma unroll
        for (int n = 0; n < 2; ++n)
            acc[m][n] = (f32x16)(0.f);

    bf16x8 fa[4][2], fb[4][2];   // fragment registers for the upcoming tap

// A-interval fragment load: tap T2 (static), from X buffer base XB
#define LOADFRAGS(T2, XB)                                                         \
    {                                                                             \
        const char* Wb_ = Wsb + ((T2) % 3) * WBUF_BYTES;                          \
        _Pragma("unroll")                                                         \
        for (int q = 0; q < 4; ++q) {                                             \
            int g = (q << 1) + (lane >> 5);                                       \
            _Pragma("unroll")                                                     \
            for (int m = 0; m < 2; ++m) {                                         \
                int cr = wr * 64 + m * 32 + l31;                                  \
                fa[q][m] = *(const bf16x8*)(Wb_ + cr * 128 + ((g ^ (cr & 7)) << 4)); \
            }                                                                     \
            _Pragma("unroll")                                                     \
            for (int n = 0; n < 2; ++n) {                                         \
                int ry = wn * 2 + n + ((T2) / 3);                                 \
                int rx = l31 + ((T2) % 3);                                        \
                fb[q][n] = *(const bf16x8*)((XB) + ((wb * 6 + ry) * 34 + rx) * 128 + \
                                            ((g ^ (rx & 7)) << 4));               \
            }                                                                     \
        }                                                                         \
    }

#define DOMFMA()                                                                  \
    {                                                                             \
        __builtin_amdgcn_s_setprio(1);                                            \
        _Pragma("unroll")                                                         \
        for (int q = 0; q < 4; ++q)                                               \
            _Pragma("unroll")                                                     \
            for (int m = 0; m < 2; ++m)                                           \
                _Pragma("unroll")                                                 \
                for (int n = 0; n < 2; ++n)                                       \
                    acc[m][n] = __builtin_amdgcn_mfma_f32_32x32x16_bf16(          \
                        fa[q][m], fb[q][n], acc[m][n], 0, 0, 0);                  \
        __builtin_amdgcn_s_setprio(0);                                            \
    }

// One stage: B2; lgkm; MFMA(T); vmcnt(ledger); B1; A-interval for stage s+1.
#define STAGE(T)                                                                  \
    {                                                                             \
        SBAR(); SCHED0();                                                         \
        asm volatile("s_waitcnt lgkmcnt(0)" ::: "memory"); SCHED0();              \
        DOMFMA();                                                                 \
        if (!((T) == 8 && cc == 7)) {                                             \
            SCHED0();                                                             \
            if ((T) == 0) {                                                       \
                if (cc < 7) asm volatile("s_waitcnt vmcnt(8)" ::: "memory");      \
                else        asm volatile("s_waitcnt vmcnt(2)" ::: "memory");      \
            } else if ((T) == 7) {                                                \
                if (cc == 7) asm volatile("s_waitcnt vmcnt(0)" ::: "memory");     \
                else         asm volatile("s_waitcnt vmcnt(2)" ::: "memory");     \
            } else {                                                              \
                asm volatile("s_waitcnt vmcnt(2)" ::: "memory");                  \
            }                                                                     \
            SCHED0(); SBAR(); SCHED0();                                           \
            if ((T) < 8) { LOADFRAGS((T) + 1, Xcur); }                            \
            else         { LOADFRAGS(0, Xnxt); }                                  \
            if ((T) == 8 && cc <= 5) issueX(Xcur, (cc + 2) * 64);                 \
            if (cc < 7 || (T) <= 5)                                               \
                issueW(((T) + 3) % 9, (((T) >= 6) ? cc + 1 : cc) * 64, (T) % 3);  \
            SCHED0();                                                             \
        }                                                                         \
    }

    // ---- prologue: W(0)->buf0, W(1)->buf1, X(0)->Xbuf0; full drain; barrier; A_0
    issueW(0, 0, 0);
    issueW(1, 0, 1);
    issueX(Xs, 0);
    SCHED0();
    asm volatile("s_waitcnt lgkmcnt(0) vmcnt(0)" ::: "memory");
    SCHED0();
    SBAR();
    SCHED0();
    LOADFRAGS(0, Xs);                 // frags for tap 0, cc 0
    issueX(Xs + XS_BYTES, 64);        // X(1)
    issueW(2, 0, 2);                  // W stage 2
    SCHED0();

    for (int cc = 0; cc < 8; ++cc) {
        char* Xcur = Xs + (cc & 1) * XS_BYTES;
        char* Xnxt = Xs + ((cc + 1) & 1) * XS_BYTES;
        STAGE(0) STAGE(1) STAGE(2) STAGE(3) STAGE(4)
        STAGE(5) STAGE(6) STAGE(7) STAGE(8)
    }

    // epilogue: demod-scale + store f32. 32x32 C layout: col=lane&31, row=(r&3)+8*(r>>2)+4*(lane>>5)
#pragma unroll
    for (int m = 0; m < 2; ++m) {
#pragma unroll
        for (int r = 0; r < 16; ++r) {
            int co = co0 + wr * 64 + m * 32 + (r & 3) + ((r >> 2) << 3) + ((lane >> 5) << 2);
            float dvv = dvec[b * CO + co];
            float* orow = out + ((size_t)b * CO + co) * HW + p0 + wn * 64;
            orow[lane & 31]        = acc[m][0][r] * dvv;
            orow[32 + (lane & 31)] = acc[m][1][r] * dvv;
        }
    }
}

extern "C" void kernel_launch(void* const* d_in, const int* in_sizes, int n_in,
                              void* d_out, int out_size, void* d_ws, size_t ws_size,
                              hipStream_t stream) {
    const float* x  = (const float*)d_in[0];
    const float* w  = (const float*)d_in[1];
    const float* sw = (const float*)d_in[2];
    const float* sb = (const float*)d_in[3];
    const float* wt = (const float*)d_in[4];
    float* out = (float*)d_out;

    char* ws = (char*)d_ws;
    float* style = (float*)(ws);                               // 32 KB
    float* dvec  = (float*)(ws + 32768);                       // 32 KB
    float* wsq   = (float*)(ws + 65536);                       // 1 MB
    __hip_bfloat16* wtb = (__hip_bfloat16*)(ws + 1114112);     // 4.72 MB
    __hip_bfloat16* xsb = (__hip_bfloat16*)(ws + 5832704);     // 16.78 MB
    char* zpage = ws + 22609920;                               // 1 KB zero page

    hipFuncSetAttribute((const void*)k_conv,
                        hipFuncAttributeMaxDynamicSharedMemorySize, SMEM_TOTAL);

    k_prep<<<3072, 256, 0, stream>>>(w, sw, sb, wt, style, wsq,
                                     (__hip_bfloat16*)wtb, (u32x4*)zpage);
    k_xs2<<<6144, 256, 0, stream>>>(x, style, wsq, xsb, dvec);
    k_conv<<<256, 512, SMEM_TOTAL, stream>>>(wtb, xsb, dvec, zpage, out);
}

// Round 17
// 88.182 us; speedup vs baseline: 1.1096x; 1.1096x over previous
//
#include <hip/hip_runtime.h>
#include <hip/hip_bf16.h>

#define NB 16
#define CI 512
#define CO 512
#define HW 1024
#define SD 512
#define EPSI 1e-8f

typedef __attribute__((ext_vector_type(8))) short bf16x8;
typedef __attribute__((ext_vector_type(16))) float f32x16;
typedef __attribute__((ext_vector_type(4))) unsigned int u32x4;

#define GLOAD_LDS16(g, l) __builtin_amdgcn_global_load_lds( \
    (const __attribute__((address_space(1))) unsigned int*)(const void*)(g), \
    (__attribute__((address_space(3))) unsigned int*)(void*)(l), 16, 0, 0)
#define SCHED0() __builtin_amdgcn_sched_barrier(0)
#define SBAR()   __builtin_amdgcn_s_barrier()

// ---- merged prep: blocks 0..2047 style GEMV; blocks 2048..3071 wprep (+zpage)
__global__ void k_prep(const float* __restrict__ w, const float* __restrict__ sw,
                       const float* __restrict__ sb, const float* __restrict__ wt,
                       float* __restrict__ style, float* __restrict__ wsq,
                       __hip_bfloat16* __restrict__ wtb, u32x4* __restrict__ zpage) {
    if (blockIdx.x < 2048) {
        int gw = (blockIdx.x * 256 + threadIdx.x) >> 6;   // 0..8191
        int l = threadIdx.x & 63;
        int b = gw >> 9, c = gw & 511;
        const float4* wr = (const float4*)(w + b * SD) + (l << 1);
        const float4* sr = (const float4*)(sw + c * SD) + (l << 1);
        float4 a0 = wr[0], a1 = wr[1], q0 = sr[0], q1 = sr[1];
        float acc = a0.x * q0.x + a0.y * q0.y + a0.z * q0.z + a0.w * q0.w
                  + a1.x * q1.x + a1.y * q1.y + a1.z * q1.z + a1.w * q1.w;
#pragma unroll
        for (int off = 32; off > 0; off >>= 1) acc += __shfl_down(acc, off);
        if (l == 0) style[gw] = acc + sb[c];
    } else {
        if (blockIdx.x == 2048 && threadIdx.x < 64)
            zpage[threadIdx.x] = (u32x4){0, 0, 0, 0};
        int idx = (blockIdx.x - 2048) * 256 + threadIdx.x;   // co*512+ci
        const float* p = wt + (size_t)idx * 9;
        float a = 0.f;
#pragma unroll
        for (int t = 0; t < 9; ++t) {
            float v = p[t];
            a += v * v;
            wtb[t * (CO * CI) + idx] = __float2bfloat16(v);
        }
        wsq[idx] = a;
    }
}

// ---- merged: blocks 0..4095 xs-transpose (short8 stores); blocks 4096..6143 demod
__global__ void k_xs2(const float* __restrict__ x, const float* __restrict__ style,
                      const float* __restrict__ wsq, __hip_bfloat16* __restrict__ xs,
                      float* __restrict__ dv) {
    __shared__ float tile[32][66];     // [px][ci], +2 pad
    if (blockIdx.x < 4096) {
        int b = blockIdx.x >> 8, c0 = ((blockIdx.x >> 5) & 7) * 64, p0 = (blockIdx.x & 31) * 32;
        int tx = threadIdx.x & 31, ty = threadIdx.x >> 5;   // ty 0..7
#pragma unroll
        for (int i = 0; i < 8; ++i) {
            int ci = i * 8 + ty;
            tile[tx][ci] = x[((size_t)b * CI + c0 + ci) * HW + p0 + tx] * style[b * CI + c0 + ci];
        }
        __syncthreads();
        int r = threadIdx.x >> 3, kc = threadIdx.x & 7;
        union { bf16x8 v; __hip_bfloat16 h[8]; } U;
#pragma unroll
        for (int i = 0; i < 8; ++i)
            U.h[i] = __float2bfloat16(tile[r][kc * 8 + i]);
        *(bf16x8*)(xs + ((size_t)b * HW + p0 + r) * CI + c0 + kc * 8) = U.v;
    } else {
        int gw = ((blockIdx.x - 4096) * 256 + threadIdx.x) >> 6;   // 0..8191
        int l = threadIdx.x & 63;
        int b = gw >> 9, co = gw & 511;
        const float4* st = (const float4*)(style + b * CI) + (l << 1);
        const float4* wq = (const float4*)(wsq + (size_t)co * CI) + (l << 1);
        float4 s0 = st[0], s1 = st[1], q0 = wq[0], q1 = wq[1];
        float acc = s0.x * s0.x * q0.x + s0.y * s0.y * q0.y + s0.z * s0.z * q0.z + s0.w * s0.w * q0.w
                  + s1.x * s1.x * q1.x + s1.y * s1.y * q1.y + s1.z * s1.z * q1.z + s1.w * s1.w * q1.w;
#pragma unroll
        for (int off = 32; off > 0; off >>= 1) acc += __shfl_down(acc, off);
        if (l == 0) dv[gw] = rsqrtf(acc + EPSI);
    }
}

// ---- conv (champion, verbatim R12/R14): 1 block = 128co x 256px x 1 batch; 8 waves =
// 2 K-halves x 4 px-quarters, per-wave m4n2 (128co x 64px, K=32 of each CK=64 chunk).
// X double-buffer (10-row halo), W triple-buffer (depth-2), counted vmcnt, setprio.
// Epilogue: K-half reduction via LDS + demod scale. 256 blocks, 1/CU, 2 waves/SIMD.
#define XS_BYTES 43520               // one X buffer: 10 rows x 34 cols x 128 B
#define WBUF_BYTES 16384             // one W buffer: 128co x 64ci bf16
#define SMEM_TOTAL (2 * XS_BYTES + 3 * WBUF_BYTES)   // 136192

extern "C" __global__ __launch_bounds__(512, 2) void k_conv(
        const __hip_bfloat16* __restrict__ wtb,
        const __hip_bfloat16* __restrict__ xs,
        const float* __restrict__ dvec,
        const char* __restrict__ zpage,
        float* __restrict__ out) {
    extern __shared__ char smem[];
    char* Xs  = smem;                    // 2 buffers
    char* Wsb = smem + 2 * XS_BYTES;     // 3 buffers

    const int tid  = threadIdx.x;
    const int lane = tid & 63;
    const int l31  = lane & 31;
    const int wv   = tid >> 6;           // 0..7
    const int kh   = wv >> 2;            // K-half (ci 0..31 / 32..63 of each chunk)
    const int wn   = wv & 3;             // px quarter (64 px each)

    // XCD swizzle: co-panel pinned per XCD pair (1.18 MB W panel L2-resident)
    int bid = blockIdx.x;
    int xcd = bid & 7, idx = bid >> 3;   // idx 0..31
    const int cot = xcd >> 1;
    const int px4 = idx & 3;
    const int b   = (idx >> 2) | ((xcd & 1) << 3);
    const int co0 = cot * 128;
    const int p0  = px4 * 256;
    const int y0  = px4 * 8;

    // zero halo pad columns rx=0 and rx=33 in BOTH X buffers (persist main loop)
    if (tid < 320) {
        int bufi = tid / 160, r = tid % 160;
        int g = r & 7;
        int rx = (r & 8) ? 33 : 0;
        int row = r >> 4;                // 0..9
        *(u32x4*)(Xs + bufi * XS_BYTES + (row * 34 + rx) * 128 + g * 16) = (u32x4){0, 0, 0, 0};
    }

    const int srcgW = (lane & 7) ^ (lane >> 3);

    // W stage: 16 segments of 1024 B, 2 per wave. tap-stage s -> buffer s%3
    auto issueW = [&](int tap, int cin, int bufi) {
        const __hip_bfloat16* wsrc = wtb + ((size_t)tap * CO + co0) * CI + cin;
        char* wdst = Wsb + bufi * WBUF_BYTES;
#pragma unroll
        for (int k = 0; k < 2; ++k) {
            int seg = k * 8 + wv;
            int co_l = seg * 8 + (lane >> 3);
            GLOAD_LDS16(wsrc + co_l * CI + srcgW * 8, wdst + seg * 1024);
        }
    };
    // X stage: 40 segments (10 rows x 4 col-groups), 5 per wave; OOB rows via zpage
    auto issueX = [&](char* Xdst, int cin) {
#pragma unroll
        for (int k = 0; k < 5; ++k) {
            int u = k * 8 + wv;          // 0..39
            int ry = u >> 2, sub = u & 3;
            int rx0 = 1 + sub * 8;
            char* ldst = Xdst + (ry * 34 + rx0) * 128;
            int y = y0 - 1 + ry;
            int rx = rx0 + (lane >> 3);
            int srcg = (lane & 7) ^ (rx & 7);
            if ((unsigned)y < 32u)
                GLOAD_LDS16(xs + ((size_t)b * HW + (y << 5) + (rx - 1)) * CI + cin + srcg * 8, ldst);
            else
                GLOAD_LDS16(zpage, ldst);   // uniform zero source (uniform ledger)
        }
    };

    f32x16 acc[4][2];
#pragma unroll
    for (int m = 0; m < 4; ++m)
#pragma unroll
        for (int n = 0; n < 2; ++n)
            acc[m][n] = (f32x16)(0.f);

    // ---- prologue: W(0)->buf0, W(1)->buf1, X(0)->Xbuf0; full drain; barrier
    issueW(0, 0, 0);
    issueW(1, 0, 1);
    issueX(Xs, 0);
    SCHED0();
    asm volatile("s_waitcnt lgkmcnt(0) vmcnt(0)" ::: "memory");
    SCHED0();
    SBAR();
    SCHED0();

    for (int cc = 0; cc < 8; ++cc) {
        const char* Xcur = Xs + (cc & 1) * XS_BYTES;
#pragma unroll
        for (int t = 0; t < 9; ++t) {
            // ---- post-barrier issue region: W(s+2) depth-2, X(cc+1) at tap0
            if (!(cc == 7 && t >= 7)) {
                const int tn  = (t <= 6) ? (t + 2) : (t - 7);
                const int cin = ((t <= 6) ? cc : (cc + 1)) * 64;
                issueW(tn, cin, (t + 2) % 3);
            }
            if (t == 0 && cc < 7)
                issueX(Xs + ((cc + 1) & 1) * XS_BYTES, (cc + 1) * 64);
            SCHED0();

            // ---- compute tap t (K-half kh) from W buffer t%3
            const char* Wb = Wsb + (t % 3) * WBUF_BYTES;
            const int ky = t / 3, kx = t - (t / 3) * 3;
            __builtin_amdgcn_s_setprio(1);
#pragma unroll
            for (int ql = 0; ql < 2; ++ql) {
                int g = kh * 4 + ql * 2 + (lane >> 5);
                bf16x8 afr[4], bfr[2];
#pragma unroll
                for (int m = 0; m < 4; ++m) {
                    int cr = m * 32 + l31;
                    afr[m] = *(const bf16x8*)(Wb + cr * 128 + ((g ^ (cr & 7)) << 4));
                }
#pragma unroll
                for (int n = 0; n < 2; ++n) {
                    int row = wn * 2 + n + ky;
                    int rx = l31 + kx;
                    bfr[n] = *(const bf16x8*)(Xcur + (row * 34 + rx) * 128 + ((g ^ (rx & 7)) << 4));
                }
#pragma unroll
                for (int m = 0; m < 4; ++m)
#pragma unroll
                    for (int n = 0; n < 2; ++n)
                        acc[m][n] = __builtin_amdgcn_mfma_f32_32x32x16_bf16(afr[m], bfr[n], acc[m][n], 0, 0, 0);
            }
            __builtin_amdgcn_s_setprio(0);

            // ---- pre-barrier counted wait (per-wave ledger, in-order retire):
            // cc<7:  t=0,1 -> after W(s+1): W(s+2)(2) + X'(5) = 7 ; t>=2 -> 2
            // cc==7: t<7 -> 2 ; t==7 -> 0 (last W) ; t==8 -> lgkm only (epilogue barrier)
            SCHED0();
            if (cc == 7 && t == 8) {
                asm volatile("s_waitcnt lgkmcnt(0)" ::: "memory");
            } else if (cc < 7 && t < 2) {
                asm volatile("s_waitcnt lgkmcnt(0) vmcnt(7)" ::: "memory");
            } else if (cc == 7 && t == 7) {
                asm volatile("s_waitcnt lgkmcnt(0) vmcnt(0)" ::: "memory");
            } else {
                asm volatile("s_waitcnt lgkmcnt(0) vmcnt(2)" ::: "memory");
            }
            SCHED0();
            SBAR();
            SCHED0();
        }
    }

    // ---- epilogue: K-half reduction via LDS (reuse whole smem), demod scale, store
    if (kh) {
        char* rb = smem + wn * 32768;
#pragma unroll
        for (int m = 0; m < 4; ++m)
#pragma unroll
            for (int n = 0; n < 2; ++n)
#pragma unroll
                for (int g4 = 0; g4 < 4; ++g4) {
                    float4 v = make_float4(acc[m][n][g4 * 4 + 0], acc[m][n][g4 * 4 + 1],
                                           acc[m][n][g4 * 4 + 2], acc[m][n][g4 * 4 + 3]);
                    *(float4*)(rb + ((((m * 2 + n) * 4 + g4) * 64) + lane) * 16) = v;
                }
    }
    SCHED0();
    asm volatile("s_waitcnt lgkmcnt(0)" ::: "memory");
    SCHED0();
    SBAR();
    SCHED0();
    if (!kh) {
        char* rb = smem + wn * 32768;
#pragma unroll
        for (int m = 0; m < 4; ++m) {
#pragma unroll
            for (int n = 0; n < 2; ++n)
#pragma unroll
                for (int g4 = 0; g4 < 4; ++g4) {
                    float4 v = *(const float4*)(rb + ((((m * 2 + n) * 4 + g4) * 64) + lane) * 16);
                    acc[m][n][g4 * 4 + 0] += v.x;
                    acc[m][n][g4 * 4 + 1] += v.y;
                    acc[m][n][g4 * 4 + 2] += v.z;
                    acc[m][n][g4 * 4 + 3] += v.w;
                }
#pragma unroll
            for (int r = 0; r < 16; ++r) {
                int col = m * 32 + (r & 3) + ((r >> 2) << 3) + ((lane >> 5) << 2);
                float dvv = dvec[b * CO + co0 + col];
                float* orow = out + ((size_t)b * CO + co0 + col) * HW + p0 + wn * 64;
                orow[l31]      = acc[m][0][r] * dvv;
                orow[32 + l31] = acc[m][1][r] * dvv;
            }
        }
    }
}

extern "C" void kernel_launch(void* const* d_in, const int* in_sizes, int n_in,
                              void* d_out, int out_size, void* d_ws, size_t ws_size,
                              hipStream_t stream) {
    const float* x  = (const float*)d_in[0];
    const float* w  = (const float*)d_in[1];
    const float* sw = (const float*)d_in[2];
    const float* sb = (const float*)d_in[3];
    const float* wt = (const float*)d_in[4];
    float* out = (float*)d_out;

    char* ws = (char*)d_ws;
    float* style = (float*)(ws);                               // 32 KB
    float* dvec  = (float*)(ws + 32768);                       // 32 KB
    float* wsq   = (float*)(ws + 65536);                       // 1 MB
    __hip_bfloat16* wtb = (__hip_bfloat16*)(ws + 1114112);     // 4.72 MB
    __hip_bfloat16* xsb = (__hip_bfloat16*)(ws + 5832704);     // 16.78 MB
    char* zpage = ws + 22609920;                               // 1 KB zero page

    hipFuncSetAttribute((const void*)k_conv,
                        hipFuncAttributeMaxDynamicSharedMemorySize, SMEM_TOTAL);

    k_prep<<<3072, 256, 0, stream>>>(w, sw, sb, wt, style, wsq,
                                     (__hip_bfloat16*)wtb, (u32x4*)zpage);
    k_xs2<<<6144, 256, 0, stream>>>(x, style, wsq, xsb, dvec);
    k_conv<<<256, 512, SMEM_TOTAL, stream>>>(wtb, xsb, dvec, zpage, out);
}